// Round 1
// 1845.948 us; speedup vs baseline: 1.0845x; 1.0845x over previous
//
#include <hip/hip_runtime.h>
#include <stdint.h>

// Problem constants (from reference): B=4, S=2048, IN=4096, OUT=16384
#define M_DIM 8192   // B*S
#define N_DIM 16384  // OUT
#define K_DIM 4096   // IN
#define NT (K_DIM / 64)  // 64 K-tiles of BK=64

typedef __bf16 bf16x8 __attribute__((ext_vector_type(8)));
typedef float f32x4 __attribute__((ext_vector_type(4)));
typedef unsigned short u16x8 __attribute__((ext_vector_type(8)));

// fp32 -> bf16 bits, round-to-nearest-even
__device__ inline unsigned short f2bf(float f) {
    union { float f; unsigned u; } v; v.f = f;
    unsigned u = v.u;
    return (unsigned short)((u + 0x7fffu + ((u >> 16) & 1u)) >> 16);
}

// async global->LDS, 16 bytes per lane; LDS dest = wave-uniform base + lane*16
#define GLDS16(gp, lp)                                                            \
    __builtin_amdgcn_global_load_lds(                                             \
        (const __attribute__((address_space(1))) void*)(gp),                      \
        (__attribute__((address_space(3))) void*)(lp), 16, 0, 0)

// ---------------------------------------------------------------------------
// Prepass 1: x fp32 -> bf16 bits, plus per-row sum (for the zero-point term).
// ---------------------------------------------------------------------------
__global__ __launch_bounds__(256) void convert_x_kernel(
    const float* __restrict__ x, unsigned short* __restrict__ xb,
    float* __restrict__ rowsum) {
    const int row = blockIdx.x;
    const float4* xr = (const float4*)(x + (size_t)row * K_DIM);
    ushort4* xo = (ushort4*)(xb + (size_t)row * K_DIM);
    float s = 0.f;
#pragma unroll
    for (int it = 0; it < 4; ++it) {
        int i = threadIdx.x + it * 256;
        float4 v = xr[i];
        s += v.x + v.y + v.z + v.w;
        ushort4 o;
        o.x = f2bf(v.x); o.y = f2bf(v.y); o.z = f2bf(v.z); o.w = f2bf(v.w);
        xo[i] = o;
    }
    __shared__ float red[256];
    red[threadIdx.x] = s;
    __syncthreads();
    for (int off = 128; off > 0; off >>= 1) {
        if (threadIdx.x < off) red[threadIdx.x] += red[threadIdx.x + off];
        __syncthreads();
    }
    if (threadIdx.x == 0) rowsum[row] = red[0];
}

// ---------------------------------------------------------------------------
// Prepass 2: weight int32 -> bf16 bits ([-128,127] exact in bf16).
// ---------------------------------------------------------------------------
__global__ __launch_bounds__(256) void convert_w_kernel(
    const int* __restrict__ wq, unsigned short* __restrict__ wb) {
    const size_t t = (size_t)blockIdx.x * 256 + threadIdx.x;
    const int4* p = (const int4*)wq + t * 2;
    int4 a = p[0], b = p[1];
    u16x8 o;
    o[0] = f2bf((float)a.x); o[1] = f2bf((float)a.y);
    o[2] = f2bf((float)a.z); o[3] = f2bf((float)a.w);
    o[4] = f2bf((float)b.x); o[5] = f2bf((float)b.y);
    o[6] = f2bf((float)b.z); o[7] = f2bf((float)b.w);
    ((u16x8*)wb)[t] = o;
}

// ---------------------------------------------------------------------------
// Main GEMM: 256x256 tile, BK=64, 512 threads (8 waves, 2M x 4N), 8-phase
// schedule (T3+T4 counted vmcnt) + K-slab LDS layout with 16B-chunk XOR
// swizzle (T2) + setprio around MFMA clusters (T5) + XCD swizzle (T1).
//
// LDS: per buffer, A and B each stored as [kh][256][32] K-slabs (contiguous
// 16KB per slab => global_load_lds linear dest; swizzle via pre-swizzled
// per-lane GLOBAL source + swizzled ds_read addr: chunk' = chunk ^ ((row>>1)&3)).
//
// Phase p of tile t: (kh=p>>1, mh=p&1); 8 ds_read_b128; stage ONE slab:
//   p0: A-k1(t+1)->nxt   p1: B-k1(t+1)->nxt   p2: A-k0(t+2)->cur   p3: B-k0(t+2)->cur
// Region safety: k0 slabs of cur are last read at p1 (kh=0), freed before p2/p3
// stage into them; k1 slabs of nxt were last read at tile t-1's p3. One counted
// s_waitcnt vmcnt(4) per tile (2 slab-stages = 4 loads stay in flight), raw
// s_barrier only. Epilogue of the ledger drains with vmcnt(0) on the last 2 tiles.
// ---------------------------------------------------------------------------
#define STAGE_A(BUFOFF, TILE, KH)                                         \
    do {                                                                  \
        const unsigned short* g_ = gA + (size_t)(TILE) * 64 + (KH) * 32;  \
        unsigned short* d_ = As + (BUFOFF) + (KH) * 8192 + (w << 9);      \
        GLDS16(g_, d_);                                                   \
        GLDS16(g_ + (size_t)128 * K_DIM, d_ + 4096);                      \
    } while (0)

#define STAGE_B(BUFOFF, TILE, KH)                                         \
    do {                                                                  \
        const unsigned short* g_ = gB + (size_t)(TILE) * 64 + (KH) * 32;  \
        unsigned short* d_ = Bs + (BUFOFF) + (KH) * 8192 + (w << 9);      \
        GLDS16(g_, d_);                                                   \
        GLDS16(g_ + (size_t)128 * K_DIM, d_ + 4096);                      \
    } while (0)

#define MFMA1(MH, MI, NI, AF, BF)                                         \
    acc[(MH) * 4 + (MI)][NI] = __builtin_amdgcn_mfma_f32_16x16x32_bf16(   \
        AF, BF, acc[(MH) * 4 + (MI)][NI], 0, 0, 0)

// One phase: 8 ds_read_b128 -> stage 1 slab -> barrier -> lgkm drain ->
// 16 MFMA under setprio. Caller supplies closing barrier (and tail vmcnt).
#define PHASE(KH, MH, STAGE_STMT)                                         \
    {                                                                     \
        const unsigned short* ap =                                        \
            aBase + bufoff + (KH) * 8192 + (MH) * 2048;                   \
        const unsigned short* bp = bBase + bufoff + (KH) * 8192;          \
        bf16x8 af0 = *(const bf16x8*)(ap);                                \
        bf16x8 af1 = *(const bf16x8*)(ap + 512);                          \
        bf16x8 af2 = *(const bf16x8*)(ap + 1024);                         \
        bf16x8 af3 = *(const bf16x8*)(ap + 1536);                         \
        bf16x8 bv0 = *(const bf16x8*)(bp);                                \
        bf16x8 bv1 = *(const bf16x8*)(bp + 512);                          \
        bf16x8 bv2 = *(const bf16x8*)(bp + 1024);                         \
        bf16x8 bv3 = *(const bf16x8*)(bp + 1536);                         \
        STAGE_STMT;                                                       \
        __builtin_amdgcn_s_barrier();                                     \
        asm volatile("s_waitcnt lgkmcnt(0)" ::: "memory");                \
        __builtin_amdgcn_sched_barrier(0);                                \
        __builtin_amdgcn_s_setprio(1);                                    \
        MFMA1(MH, 0, 0, af0, bv0); MFMA1(MH, 0, 1, af0, bv1);             \
        MFMA1(MH, 0, 2, af0, bv2); MFMA1(MH, 0, 3, af0, bv3);             \
        MFMA1(MH, 1, 0, af1, bv0); MFMA1(MH, 1, 1, af1, bv1);             \
        MFMA1(MH, 1, 2, af1, bv2); MFMA1(MH, 1, 3, af1, bv3);             \
        MFMA1(MH, 2, 0, af2, bv0); MFMA1(MH, 2, 1, af2, bv1);             \
        MFMA1(MH, 2, 2, af2, bv2); MFMA1(MH, 2, 3, af2, bv3);             \
        MFMA1(MH, 3, 0, af3, bv0); MFMA1(MH, 3, 1, af3, bv1);             \
        MFMA1(MH, 3, 2, af3, bv2); MFMA1(MH, 3, 3, af3, bv3);             \
        __builtin_amdgcn_s_setprio(0);                                    \
    }

__global__ __launch_bounds__(512, 2) void gemm_kernel(
    const unsigned short* __restrict__ A, const unsigned short* __restrict__ B,
    const float* __restrict__ rowsum, const float* __restrict__ scale,
    const float* __restrict__ zp, const float* __restrict__ bias,
    float* __restrict__ C) {
    // [buf 2][kh 2][256 rows][32 cols] bf16 = 64 KiB each; total 128 KiB
    __shared__ __align__(16) unsigned short As[2 * 2 * 8192];
    __shared__ __align__(16) unsigned short Bs[2 * 2 * 8192];

    const int t = threadIdx.x;
    const int w = t >> 6;   // wave 0..7
    const int l = t & 63;   // lane
    const int wm = w & 1;   // 2 waves along M (128 rows each)
    const int wn = w >> 1;  // 4 waves along N (64 cols each)

    // XCD-aware bijective swizzle: nwg=2048, 2048%8==0. n-fast within XCD
    // so the 4 A-panels per XCD stay L2-resident across 64 n-tiles.
    const int bid = blockIdx.x;
    const int swz = (bid & 7) * 256 + (bid >> 3);
    const int tileN = (swz & 63) << 8;
    const int tileM = (swz >> 6) << 8;

    // --- staging: lane l of wave w covers slab row w*16 + l/4, 16B chunk
    // (l&3) ^ ((l>>3)&3)  [= inverse swizzle on the GLOBAL source, rule #21]
    const int srow = (w << 4) + (l >> 2);
    const int scol = ((l & 3) ^ ((l >> 3) & 3)) << 3;  // elements
    const unsigned short* gA = A + (size_t)(tileM + srow) * K_DIM + scol;
    const unsigned short* gB = B + (size_t)(tileN + srow) * K_DIM + scol;

    // --- fragment read bases: row = <const> + (l&15), phys chunk = lk ^ ((row>>1)&3)
    const int lrow = l & 15, lk4 = l >> 4;
    const int cph = (lk4 ^ ((l >> 1) & 3)) << 3;  // elements
    const unsigned short* aBase = As + (wm * 128 + lrow) * 32 + cph;
    const unsigned short* bBase = Bs + (wn * 64 + lrow) * 32 + cph;

    f32x4 acc[8][4];
#pragma unroll
    for (int i = 0; i < 8; ++i)
#pragma unroll
        for (int j = 0; j < 4; ++j) acc[i][j] = f32x4{0.f, 0.f, 0.f, 0.f};

    // --- prologue: tile0 all 4 slabs + tile1 k0 slabs (6 ops = 12 loads);
    // vmcnt(4) leaves tile1-k0 (2 ops) in flight.
    STAGE_A(0, 0, 0); STAGE_B(0, 0, 0);
    STAGE_A(0, 0, 1); STAGE_B(0, 0, 1);
    STAGE_A(16384, 1, 0); STAGE_B(16384, 1, 0);
    asm volatile("s_waitcnt vmcnt(4)" ::: "memory");
    __builtin_amdgcn_s_barrier();

#pragma unroll 2
    for (int tt = 0; tt < NT; ++tt) {
        const int bufoff = (tt & 1) << 14;  // element offset, *16384
        const int nbufoff = bufoff ^ 16384;
        const bool st1 = (tt + 1) < NT;
        const bool st2 = (tt + 2) < NT;

        PHASE(0, 0, if (st1) STAGE_A(nbufoff, tt + 1, 1));
        __builtin_amdgcn_s_barrier();
        PHASE(0, 1, if (st1) STAGE_B(nbufoff, tt + 1, 1));
        __builtin_amdgcn_s_barrier();
        PHASE(1, 0, if (st2) STAGE_A(bufoff, tt + 2, 0));
        __builtin_amdgcn_s_barrier();
        PHASE(1, 1, if (st2) STAGE_B(bufoff, tt + 2, 0));
        if (tt < NT - 2)
            asm volatile("s_waitcnt vmcnt(4)" ::: "memory");
        else
            asm volatile("s_waitcnt vmcnt(0)" ::: "memory");
        __builtin_amdgcn_s_barrier();
    }

    // --- epilogue: C/D layout col=lane&15, row=(lane>>4)*4+reg
    const int nb = tileN + wn * 64 + lrow;
    float sc[4], szp[4], bs[4];
#pragma unroll
    for (int ni = 0; ni < 4; ++ni) {
        int n = nb + ni * 16;
        float s = scale[n];
        sc[ni] = s;
        szp[ni] = s * zp[n];
        bs[ni] = bias[n];
    }
    const int mb = tileM + wm * 128 + lk4 * 4;
#pragma unroll
    for (int mi = 0; mi < 8; ++mi) {
#pragma unroll
        for (int i = 0; i < 4; ++i) {
            int m = mb + mi * 16 + i;
            float rs = rowsum[m];
            float* orow = C + (size_t)m * N_DIM + nb;
#pragma unroll
            for (int ni = 0; ni < 4; ++ni)
                orow[ni * 16] = acc[mi][ni][i] * sc[ni] + bs[ni] - szp[ni] * rs;
        }
    }
}

// ---------------------------------------------------------------------------
// Fallback (only if ws_size too small): fp32 LDS-tiled GEMM, correct but slow.
// ---------------------------------------------------------------------------
__global__ __launch_bounds__(256) void fallback_kernel(
    const float* __restrict__ x, const int* __restrict__ wq,
    const float* __restrict__ scale, const float* __restrict__ zp,
    const float* __restrict__ bias, float* __restrict__ C) {
    __shared__ float Asf[64][33];
    __shared__ float Bsf[64][33];
    const int tileM = blockIdx.y * 64, tileN = blockIdx.x * 64;
    const int tx = threadIdx.x & 15, ty = threadIdx.x >> 4;
    float accq[4][4] = {};
    float rsum[4] = {};
    for (int k0 = 0; k0 < K_DIM; k0 += 32) {
        for (int i = threadIdx.x; i < 64 * 32; i += 256) {
            int r = i >> 5, c = i & 31;
            Asf[r][c] = x[(size_t)(tileM + r) * K_DIM + k0 + c];
            Bsf[r][c] = (float)wq[(size_t)(tileN + r) * K_DIM + k0 + c];
        }
        __syncthreads();
        for (int kk = 0; kk < 32; ++kk) {
            float av[4], bv[4];
#pragma unroll
            for (int j = 0; j < 4; ++j) av[j] = Asf[ty * 4 + j][kk];
#pragma unroll
            for (int j = 0; j < 4; ++j) bv[j] = Bsf[tx * 4 + j][kk];
#pragma unroll
            for (int i = 0; i < 4; ++i) {
                rsum[i] += av[i];
#pragma unroll
                for (int j = 0; j < 4; ++j) accq[i][j] += av[i] * bv[j];
            }
        }
        __syncthreads();
    }
#pragma unroll
    for (int i = 0; i < 4; ++i) {
        int m = tileM + ty * 4 + i;
#pragma unroll
        for (int j = 0; j < 4; ++j) {
            int n = tileN + tx * 4 + j;
            C[(size_t)m * N_DIM + n] =
                scale[n] * accq[i][j] - scale[n] * zp[n] * rsum[i] + bias[n];
        }
    }
}

extern "C" void kernel_launch(void* const* d_in, const int* in_sizes, int n_in,
                              void* d_out, int out_size, void* d_ws, size_t ws_size,
                              hipStream_t stream) {
    const float* x = (const float*)d_in[0];
    const int* wq = (const int*)d_in[1];  // int32 per element, N_DIM x K_DIM
    const float* scale = (const float*)d_in[2];
    const float* zp = (const float*)d_in[3];
    const float* bias = (const float*)d_in[4];
    float* out = (float*)d_out;

    const size_t xb_bytes = (size_t)M_DIM * K_DIM * 2;  // 64 MiB
    const size_t wb_bytes = (size_t)N_DIM * K_DIM * 2;  // 128 MiB
    const size_t need = xb_bytes + wb_bytes + (size_t)M_DIM * 4;

    if (ws_size >= need) {
        unsigned short* xb = (unsigned short*)d_ws;
        unsigned short* wb = (unsigned short*)((char*)d_ws + xb_bytes);
        float* rowsum = (float*)((char*)d_ws + xb_bytes + wb_bytes);
        convert_x_kernel<<<M_DIM, 256, 0, stream>>>(x, xb, rowsum);
        const int wblocks = (int)(((size_t)N_DIM * K_DIM) / 8 / 256);  // 32768
        convert_w_kernel<<<wblocks, 256, 0, stream>>>(wq, wb);
        const int nwg = (N_DIM / 256) * (M_DIM / 256);  // 64*32 = 2048
        gemm_kernel<<<nwg, 512, 0, stream>>>(xb, wb, rowsum, scale, zp, bias, out);
    } else {
        dim3 grid(N_DIM / 64, M_DIM / 64);
        fallback_kernel<<<grid, 256, 0, stream>>>(x, wq, scale, zp, bias, out);
    }
}